// Round 5
// baseline (634.365 us; speedup 1.0000x reference)
//
#include <hip/hip_runtime.h>

// Residual VQ, Q=4 stages. R12 = R11 tiling (8 pts x 8 codes per thread, 64-reg
// acc, per-lane-optimal 4 b128 LDS reads per 64 FMAs) with the register budget
// fixed: __launch_bounds__(256, 2). Empirical: arg=3 @256thr lands the allocator
// at ~84 VGPR (6 waves/EU) -> spills (R7: 84/spill, R11: 84/spill, 199MB WRITE);
// arg=2 allocs cleanly (R9: 120, R10: 112). Single-variable change vs R11.
//
// d_out: quantized [8,64,128,128] (8388608 f32) | indices as float
//        [8,128,128,4] (524288) | commit_loss [4].
// d_ws: cbS [64][512] striped transposed codebook + csqS [512] (striped -csq/2).

#define NPTS   131072
#define CH     64
#define KCODE  512
#define NQ     4
#define HW     16384
#define BPTS   32        // points per block
#define BTHR   256       // threads per block (4 waves)
#define CCH    8         // channels per chunk
#define NCHK   8         // chunks per stage (CH / CCH)

__device__ __forceinline__ void load_lds16(const float* g, float* l) {
    __builtin_amdgcn_global_load_lds(
        (const __attribute__((address_space(1))) void*)g,
        (__attribute__((address_space(3))) void*)l, 16, 0, 0);
}

// Striped layout: pos(k) = nb*256 + g*4 + j for k = g*8 + nb*4 + j, g=0..63.
// cbS[c*512 + pos] = cb[k*64 + c]. A wave (lane=g) reading float4 at
// c*512 + nb*256 + lane*4 covers one contiguous 1KB line -> conflict-free.
__global__ void prep_cbS(const float* __restrict__ cb, float* __restrict__ cbS) {
    int gi = blockIdx.x * 256 + threadIdx.x;   // 0..32767
    int c = gi >> 9, pos = gi & 511;
    int nb = pos >> 8, g = (pos >> 2) & 63, j = pos & 3;
    int k = g * 8 + nb * 4 + j;
    cbS[gi] = cb[k * CH + c];
}

// csqS[pos(k)] = -0.5 * ||cb[k]||^2, same striped layout.
__global__ void prep_csq(const float* __restrict__ cb, float* __restrict__ csqS) {
    int k = blockIdx.x * 256 + threadIdx.x;
    if (k < KCODE) {
        const float4* row = (const float4*)(cb + (size_t)k * CH);
        float a0 = 0.f, a1 = 0.f, a2 = 0.f, a3 = 0.f;
#pragma unroll
        for (int j = 0; j < CH / 4; ++j) {
            float4 v = row[j];
            a0 = fmaf(v.x, v.x, a0); a1 = fmaf(v.y, v.y, a1);
            a2 = fmaf(v.z, v.z, a2); a3 = fmaf(v.w, v.w, a3);
        }
        float s = (a0 + a1) + (a2 + a3);
        int g = k >> 3, nb = (k >> 2) & 1, j = k & 3;
        csqS[nb * 256 + g * 4 + j] = -0.5f * s;
    }
}

__global__ __launch_bounds__(BTHR, 2) void rvq_main(
    const float* __restrict__ x, const float* __restrict__ cb,
    const float* __restrict__ cbS, const float* __restrict__ csq_g,
    float* __restrict__ out_quant, float* __restrict__ out_idx,
    float* __restrict__ out_loss)
{
    __shared__ __align__(16) float s_res[CH * BPTS];        // 8 KB residual [c][p]
    __shared__ __align__(16) float s_buf[2][CCH * KCODE];   // 2 x 16 KB chunk buffers
    __shared__ __align__(16) float s_csq[KCODE];            // 2 KB (striped -csq/2)
    __shared__ int   s_bidx[BPTS];                          // 128 B
    __shared__ int   s_idx4[BPTS * NQ];                     // 512 B
    __shared__ float s_ls[8 * BPTS];                        // 1 KB

    const int tid  = threadIdx.x;
    const int lane = tid & 63;   // code group: codes k = lane*8 + nb*4 + j
    const int wv   = tid >> 6;   // wave 0..3: points p = wv*8 .. wv*8+7

    const int n0  = blockIdx.x * BPTS;   // block never straddles batch index
    const int b   = n0 >> 14;
    const int hw0 = n0 & (HW - 1);
    const float* xbase = x + (size_t)b * CH * HW + hw0;

    // ---- prefetch stage-0 chunk 0 into buf[0] (overlaps x-tile load) ----
#pragma unroll
    for (int r = 0; r < 4; ++r) {
        int off = (wv * 4 + r) * 256;
        load_lds16(cbS + off + lane * 4, &s_buf[0][off]);
    }

    // ---- x tile -> s_res, striped -csq/2 -> s_csq ----
    for (int j = tid; j < CH * BPTS / 4; j += BTHR) {
        int c = j >> 3, p4 = j & 7;
        *(float4*)&s_res[c * BPTS + p4 * 4] =
            *(const float4*)(xbase + (size_t)c * HW + p4 * 4);
    }
    for (int j = tid; j < KCODE; j += BTHR) s_csq[j] = csq_g[j];
    __syncthreads();   // s_res/s_csq visible, buf[0] drained

    for (int q = 0; q < NQ; ++q) {
        // ---- acc init = -csq/2 (contiguous b128 reads, striped layout) ----
        float acc[8][8];
        {
            const float* cqp = s_csq + lane * 4;
#pragma unroll
            for (int nb = 0; nb < 2; ++nb) {
                float4 iv = *(const float4*)(cqp + nb * 256);
#pragma unroll
                for (int p = 0; p < 8; ++p) {
                    acc[p][nb * 4 + 0] = iv.x; acc[p][nb * 4 + 1] = iv.y;
                    acc[p][nb * 4 + 2] = iv.z; acc[p][nb * 4 + 3] = iv.w;
                }
            }
        }

        // ---- GEMM: 8 chunks x 8 channels, double-buffered ----
        for (int chk = 0; chk < NCHK; ++chk) {
            // prefetch next chunk (chunk 0 of next stage on wrap) into the
            // other buffer; it has the whole current chunk's compute to land.
            if (!(q == NQ - 1 && chk == NCHK - 1)) {
                const int nchk = (chk + 1 < NCHK) ? chk + 1 : 0;
                const float* src = cbS + nchk * (CCH * KCODE);
                float* dst = s_buf[(chk + 1) & 1];
#pragma unroll
                for (int r = 0; r < 4; ++r) {
                    int off = (wv * 4 + r) * 256;
                    load_lds16(src + off + lane * 4, dst + off);
                }
            }

            const float* bufp = s_buf[chk & 1];
#pragma unroll 2
            for (int c = 0; c < CCH; ++c) {
                const float* ar = &s_res[(chk * CCH + c) * BPTS + wv * 8];
                float4 a0 = *(const float4*)(ar);
                float4 a1 = *(const float4*)(ar + 4);
                float av[8] = {a0.x, a0.y, a0.z, a0.w, a1.x, a1.y, a1.z, a1.w};
                const float* br = &bufp[c * KCODE + lane * 4];
#pragma unroll
                for (int nb = 0; nb < 2; ++nb) {
                    float4 bq = *(const float4*)(br + nb * 256);
#pragma unroll
                    for (int p = 0; p < 8; ++p) {
                        acc[p][nb * 4 + 0] = fmaf(av[p], bq.x, acc[p][nb * 4 + 0]);
                        acc[p][nb * 4 + 1] = fmaf(av[p], bq.y, acc[p][nb * 4 + 1]);
                        acc[p][nb * 4 + 2] = fmaf(av[p], bq.z, acc[p][nb * 4 + 2]);
                        acc[p][nb * 4 + 3] = fmaf(av[p], bq.w, acc[p][nb * 4 + 3]);
                    }
                }
            }
            __syncthreads();   // all waves done with buf[chk&1]; prefetch drained
        }

        // ---- per-thread argmax over own 8 codes (ascending k, strict >) ----
        float bd[8]; int bi[8];
#pragma unroll
        for (int p = 0; p < 8; ++p) {
            float B = acc[p][0]; int I = lane * 8;
#pragma unroll
            for (int n = 1; n < 8; ++n)
                if (acc[p][n] > B) { B = acc[p][n]; I = lane * 8 + n; }
            bd[p] = B; bi[p] = I;
        }

        // ---- full-wave butterfly merge across 64 lanes (in-register) ----
#pragma unroll
        for (int m = 1; m <= 32; m <<= 1) {
#pragma unroll
            for (int p = 0; p < 8; ++p) {
                float oB = __shfl_xor(bd[p], m, 64);
                int   oI = __shfl_xor(bi[p], m, 64);
                if (oB > bd[p] || (oB == bd[p] && oI < bi[p])) {
                    bd[p] = oB; bi[p] = oI;
                }
            }
        }
        if (lane == 0) {
#pragma unroll
            for (int p = 0; p < 8; ++p) {
                s_bidx[wv * 8 + p] = bi[p];
                s_idx4[(wv * 8 + p) * 4 + q] = bi[p];
            }
        }
        __syncthreads();   // s_bidx visible

        // ---- residual update (exact r' = r - c) + loss partials ----
        {
            const int p  = tid & 31;
            const int c8 = tid >> 5;   // 8-channel eighth
            int bix = s_bidx[p];
            const float4* crow = (const float4*)(cb + (size_t)bix * CH + c8 * 8);
            float l0 = 0.f, l1 = 0.f, l2 = 0.f, l3 = 0.f;
#pragma unroll
            for (int i = 0; i < 2; ++i) {
                float4 v = crow[i];
                int c = c8 * 8 + i * 4;
                float r0 = s_res[(c + 0) * BPTS + p] - v.x;
                float r1 = s_res[(c + 1) * BPTS + p] - v.y;
                float r2 = s_res[(c + 2) * BPTS + p] - v.z;
                float r3 = s_res[(c + 3) * BPTS + p] - v.w;
                s_res[(c + 0) * BPTS + p] = r0;
                s_res[(c + 1) * BPTS + p] = r1;
                s_res[(c + 2) * BPTS + p] = r2;
                s_res[(c + 3) * BPTS + p] = r3;
                l0 = fmaf(r0, r0, l0); l1 = fmaf(r1, r1, l1);
                l2 = fmaf(r2, r2, l2); l3 = fmaf(r3, r3, l3);
            }
            s_ls[c8 * BPTS + p] = (l0 + l1) + (l2 + l3);
        }
        __syncthreads();   // s_res + s_ls visible

        // ---- commit-loss reduce for this stage (wave 0 only; q is uniform) ----
        if (wv == 0) {
            float v = 0.f;
            if (lane < BPTS)
                v = ((s_ls[0 * BPTS + lane] + s_ls[1 * BPTS + lane]) +
                     (s_ls[2 * BPTS + lane] + s_ls[3 * BPTS + lane])) +
                    ((s_ls[4 * BPTS + lane] + s_ls[5 * BPTS + lane]) +
                     (s_ls[6 * BPTS + lane] + s_ls[7 * BPTS + lane]));
            for (int off = 32; off > 0; off >>= 1) v += __shfl_down(v, off, 64);
            if (lane == 0)
                atomicAdd(&out_loss[q], v * (1.0f / 8388608.0f));  // /(NPTS*CH)
        }
    }

    // ---- epilogue: quantized = sum of 4 chosen code rows (sequential order) ----
    {
        const int p  = tid & 31;
        const int c8 = tid >> 5;
        int e0 = s_idx4[p * 4 + 0], e1 = s_idx4[p * 4 + 1];
        int e2 = s_idx4[p * 4 + 2], e3 = s_idx4[p * 4 + 3];
        const float4* r0 = (const float4*)(cb + (size_t)e0 * CH + c8 * 8);
        const float4* r1 = (const float4*)(cb + (size_t)e1 * CH + c8 * 8);
        const float4* r2 = (const float4*)(cb + (size_t)e2 * CH + c8 * 8);
        const float4* r3 = (const float4*)(cb + (size_t)e3 * CH + c8 * 8);
        float* ob = out_quant + (size_t)b * CH * HW + hw0;
#pragma unroll
        for (int i = 0; i < 2; ++i) {
            float4 v0 = r0[i], v1 = r1[i], v2 = r2[i], v3 = r3[i];
            float s0 = ((v0.x + v1.x) + v2.x) + v3.x;
            float s1 = ((v0.y + v1.y) + v2.y) + v3.y;
            float s2 = ((v0.z + v1.z) + v2.z) + v3.z;
            float s3 = ((v0.w + v1.w) + v2.w) + v3.w;
            int c = c8 * 8 + i * 4;
            ob[(size_t)(c + 0) * HW + p] = s0;
            ob[(size_t)(c + 1) * HW + p] = s1;
            ob[(size_t)(c + 2) * HW + p] = s2;
            ob[(size_t)(c + 3) * HW + p] = s3;
        }

        // indices (wave 0, lanes 0..31; e0..e3 already in registers)
        if (tid < BPTS)
            ((float4*)out_idx)[n0 + p] =
                make_float4((float)e0, (float)e1, (float)e2, (float)e3);
    }
}

extern "C" void kernel_launch(void* const* d_in, const int* in_sizes, int n_in,
                              void* d_out, int out_size, void* d_ws, size_t ws_size,
                              hipStream_t stream) {
    const float* x  = (const float*)d_in[0];
    const float* cb = (const float*)d_in[1];
    float* out       = (float*)d_out;
    float* out_quant = out;                    // 8388608
    float* out_idx   = out + 8388608;          // 524288
    float* out_loss  = out + 8388608 + 524288; // 4

    float* cbS = (float*)d_ws;                 // 64*512 floats (striped)
    float* csq = cbS + CH * KCODE;             // 512 floats (striped -csq/2)

    hipMemsetAsync(out_loss, 0, NQ * sizeof(float), stream);
    prep_cbS<<<(CH * KCODE) / 256, 256, 0, stream>>>(cb, cbS);
    prep_csq<<<2, 256, 0, stream>>>(cb, csq);
    rvq_main<<<NPTS / BPTS, BTHR, 0, stream>>>(x, cb, cbS, csq,
                                               out_quant, out_idx, out_loss);
}

// Round 6
// 529.329 us; speedup vs baseline: 1.1984x; 1.1984x over previous
//
#include <hip/hip_runtime.h>

// Residual VQ, Q=4 stages. R13 = R7 tile (BPTS=64, acc[8][16]: 128 FMAs per
// {4 half-broadcast B-reads + 2 uniform A-reads} -> LDS pipe ~0.9x subscribed,
// the only balanced tile of R7..R12) + __launch_bounds__(256,2) (arg=3 produced
// the 84-VGPR spilling allocation in R7/R11; arg=2 allocs clean in R9/R10/R12)
// + striped -csq/2 acc-init (R10-proven, kills 16-way-conflict init) + no
// runtime-indexed thread arrays (loss reduced inline per stage, indices from
// s_idx4 in epilogue). GEMM/argmin/residual numerics = R7's bit-exact path.
//
// d_out: quantized [8,64,128,128] (8388608 f32) | indices as float
//        [8,128,128,4] (524288) | commit_loss [4].
// d_ws: cbS [64][512] bank-striped transposed codebook + csqS [512] (striped -csq/2).

#define NPTS   131072
#define CH     64
#define KCODE  512
#define NQ     4
#define HW     16384
#define BPTS   64        // points per block
#define BTHR   256       // threads per block (4 waves)
#define CCH    8         // channels per chunk
#define NCHK   8         // chunks per stage (CH / CCH)

__device__ __forceinline__ void load_lds16(const float* g, float* l) {
    __builtin_amdgcn_global_load_lds(
        (const __attribute__((address_space(1))) void*)g,
        (__attribute__((address_space(3))) void*)l, 16, 0, 0);
}

// cbS[c*512 + pos] = cb[k*64 + c], pos(k) = i*128 + cg*4 + j for k = cg*16+i*4+j
__global__ void prep_cbS(const float* __restrict__ cb, float* __restrict__ cbS) {
    int g = blockIdx.x * 256 + threadIdx.x;   // 0..32767
    int c = g >> 9, pos = g & 511;
    int i = pos >> 7, cg = (pos >> 2) & 31, j = pos & 3;
    int k = cg * 16 + i * 4 + j;
    cbS[g] = cb[k * CH + c];
}

// csqS[pos(k)] = -0.5 * ||cb[k]||^2, same striped pos(k) mapping as cbS.
__global__ void prep_csq(const float* __restrict__ cb, float* __restrict__ csqS) {
    int k = blockIdx.x * 256 + threadIdx.x;
    if (k < KCODE) {
        const float4* row = (const float4*)(cb + (size_t)k * CH);
        float a0 = 0.f, a1 = 0.f, a2 = 0.f, a3 = 0.f;
#pragma unroll
        for (int j = 0; j < CH / 4; ++j) {
            float4 v = row[j];
            a0 = fmaf(v.x, v.x, a0); a1 = fmaf(v.y, v.y, a1);
            a2 = fmaf(v.z, v.z, a2); a3 = fmaf(v.w, v.w, a3);
        }
        float s = (a0 + a1) + (a2 + a3);
        int cg = k >> 4, i = (k & 15) >> 2, j = k & 3;
        csqS[i * 128 + cg * 4 + j] = -0.5f * s;
    }
}

__global__ __launch_bounds__(BTHR, 2) void rvq_main(
    const float* __restrict__ x, const float* __restrict__ cb,
    const float* __restrict__ cbS, const float* __restrict__ csq_g,
    float* __restrict__ out_quant, float* __restrict__ out_idx,
    float* __restrict__ out_loss)
{
    __shared__ __align__(16) float s_res[CH * BPTS];        // 16 KB residual [c][p]
    __shared__ __align__(16) float s_buf[2][CCH * KCODE];   // 2 x 16 KB chunk buffers
    __shared__ __align__(16) float s_csq[KCODE];            // 2 KB (striped -csq/2)
    __shared__ int   s_bidx[BPTS];                          // 256 B
    __shared__ int   s_idx4[BPTS * NQ];                     // 1 KB
    __shared__ float s_ls[4 * BPTS];                        // 1 KB

    const int tid  = threadIdx.x;
    const int lane = tid & 63;
    const int w    = tid >> 6;
    const int cg   = tid & 31;   // 16 codes: k = cg*16 + n
    const int pg   = tid >> 5;   // 8 points: p = pg*8 .. pg*8+7

    const int n0  = blockIdx.x * BPTS;   // block never straddles batch index
    const int b   = n0 >> 14;
    const int hw0 = n0 & (HW - 1);
    const float* xbase = x + (size_t)b * CH * HW + hw0;

    // ---- prefetch stage-0 chunk 0 into buf[0] (overlaps x-tile load) ----
#pragma unroll
    for (int r = 0; r < 4; ++r) {
        int off = (w * 4 + r) * 256;
        load_lds16(cbS + off + lane * 4, &s_buf[0][off]);
    }

    // ---- x tile -> s_res, striped -csq/2 -> s_csq ----
    for (int j = tid; j < CH * BPTS / 4; j += BTHR) {
        int c = j >> 4, p4 = j & 15;
        *(float4*)&s_res[c * BPTS + p4 * 4] =
            *(const float4*)(xbase + (size_t)c * HW + p4 * 4);
    }
    for (int j = tid; j < KCODE; j += BTHR) s_csq[j] = csq_g[j];
    __syncthreads();   // s_res/s_csq visible, buf[0] drained

    for (int q = 0; q < NQ; ++q) {
        // ---- acc init = -csq/2 (striped b128 reads, 4-way worst case) ----
        float acc[8][16];
        {
            const float* cqp = s_csq + cg * 4;
#pragma unroll
            for (int i = 0; i < 4; ++i) {
                float4 iv = *(const float4*)(cqp + i * 128);
#pragma unroll
                for (int p = 0; p < 8; ++p) {
                    acc[p][i * 4 + 0] = iv.x; acc[p][i * 4 + 1] = iv.y;
                    acc[p][i * 4 + 2] = iv.z; acc[p][i * 4 + 3] = iv.w;
                }
            }
        }

        // ---- GEMM: 8 chunks x 8 channels, double-buffered ----
        for (int chk = 0; chk < NCHK; ++chk) {
            // prefetch next chunk (chunk 0 of next stage on wrap) into the
            // other buffer; it has the whole current chunk's compute to land.
            if (!(q == NQ - 1 && chk == NCHK - 1)) {
                const int nchk = (chk + 1 < NCHK) ? chk + 1 : 0;
                const float* src = cbS + nchk * (CCH * KCODE);
                float* dst = s_buf[(chk + 1) & 1];
#pragma unroll
                for (int r = 0; r < 4; ++r) {
                    int off = (w * 4 + r) * 256;
                    load_lds16(src + off + lane * 4, dst + off);
                }
            }

            const float* bufp = s_buf[chk & 1];
#pragma unroll 2
            for (int c = 0; c < CCH; ++c) {
                const float* ar = &s_res[(chk * CCH + c) * BPTS + pg * 8];
                float4 a0 = *(const float4*)(ar + 0);
                float4 a1 = *(const float4*)(ar + 4);
                float av[8] = {a0.x, a0.y, a0.z, a0.w, a1.x, a1.y, a1.z, a1.w};
                const float* br = &bufp[c * KCODE + cg * 4];
#pragma unroll
                for (int nb = 0; nb < 4; ++nb) {
                    float4 bq = *(const float4*)(br + nb * 128);
#pragma unroll
                    for (int p = 0; p < 8; ++p) {
                        acc[p][nb * 4 + 0] = fmaf(av[p], bq.x, acc[p][nb * 4 + 0]);
                        acc[p][nb * 4 + 1] = fmaf(av[p], bq.y, acc[p][nb * 4 + 1]);
                        acc[p][nb * 4 + 2] = fmaf(av[p], bq.z, acc[p][nb * 4 + 2]);
                        acc[p][nb * 4 + 3] = fmaf(av[p], bq.w, acc[p][nb * 4 + 3]);
                    }
                }
            }
            __syncthreads();   // all waves done with buf[chk&1]; prefetch drained
        }

        // ---- per-thread argmax over own 16 codes (ascending k, strict >) ----
        float bd[8]; int bi[8];
#pragma unroll
        for (int p = 0; p < 8; ++p) {
            float B = acc[p][0]; int I = cg * 16;
#pragma unroll
            for (int n = 1; n < 16; ++n)
                if (acc[p][n] > B) { B = acc[p][n]; I = cg * 16 + n; }
            bd[p] = B; bi[p] = I;
        }

        // ---- half-wave butterfly merge across the 32 cg-lanes (in-register) ----
#pragma unroll
        for (int m = 1; m <= 16; m <<= 1) {
#pragma unroll
            for (int p = 0; p < 8; ++p) {
                float oB = __shfl_xor(bd[p], m, 64);
                int   oI = __shfl_xor(bi[p], m, 64);
                if (oB > bd[p] || (oB == bd[p] && oI < bi[p])) {
                    bd[p] = oB; bi[p] = oI;
                }
            }
        }
        if (cg == 0) {
#pragma unroll
            for (int p = 0; p < 8; ++p) {
                s_bidx[pg * 8 + p] = bi[p];
                s_idx4[(pg * 8 + p) * 4 + q] = bi[p];
            }
        }
        __syncthreads();   // s_bidx visible

        // ---- residual update (exact r' = r - c) + loss partials ----
        {
            const int p  = tid & 63;
            const int cq = tid >> 6;   // 16-channel quarter
            int bix = s_bidx[p];
            const float4* crow = (const float4*)(cb + (size_t)bix * CH + cq * 16);
            float l0 = 0.f, l1 = 0.f, l2 = 0.f, l3 = 0.f;
#pragma unroll
            for (int i = 0; i < 4; ++i) {
                float4 v = crow[i];
                int c = cq * 16 + i * 4;
                float r0 = s_res[(c + 0) * BPTS + p] - v.x;
                float r1 = s_res[(c + 1) * BPTS + p] - v.y;
                float r2 = s_res[(c + 2) * BPTS + p] - v.z;
                float r3 = s_res[(c + 3) * BPTS + p] - v.w;
                s_res[(c + 0) * BPTS + p] = r0;
                s_res[(c + 1) * BPTS + p] = r1;
                s_res[(c + 2) * BPTS + p] = r2;
                s_res[(c + 3) * BPTS + p] = r3;
                l0 = fmaf(r0, r0, l0); l1 = fmaf(r1, r1, l1);
                l2 = fmaf(r2, r2, l2); l3 = fmaf(r3, r3, l3);
            }
            s_ls[cq * BPTS + p] = (l0 + l1) + (l2 + l3);
        }
        __syncthreads();   // s_res + s_ls visible

        // ---- commit-loss reduce for this stage (wave 0; q is uniform) ----
        if (w == 0) {
            float v = (s_ls[0 * BPTS + lane] + s_ls[1 * BPTS + lane]) +
                      (s_ls[2 * BPTS + lane] + s_ls[3 * BPTS + lane]);
            for (int off = 32; off > 0; off >>= 1) v += __shfl_down(v, off, 64);
            if (lane == 0)
                atomicAdd(&out_loss[q], v * (1.0f / 8388608.0f));  // /(NPTS*CH)
        }
    }

    // ---- epilogue: quantized = sum of 4 chosen code rows (sequential order) ----
    {
        const int p  = tid & 63;
        const int cq = tid >> 6;
        int e0 = s_idx4[p * 4 + 0], e1 = s_idx4[p * 4 + 1];
        int e2 = s_idx4[p * 4 + 2], e3 = s_idx4[p * 4 + 3];
        const float4* r0 = (const float4*)(cb + (size_t)e0 * CH + cq * 16);
        const float4* r1 = (const float4*)(cb + (size_t)e1 * CH + cq * 16);
        const float4* r2 = (const float4*)(cb + (size_t)e2 * CH + cq * 16);
        const float4* r3 = (const float4*)(cb + (size_t)e3 * CH + cq * 16);
        float* ob = out_quant + (size_t)b * CH * HW + hw0;
#pragma unroll
        for (int i = 0; i < 4; ++i) {
            float4 v0 = r0[i], v1 = r1[i], v2 = r2[i], v3 = r3[i];
            float s0 = ((v0.x + v1.x) + v2.x) + v3.x;
            float s1 = ((v0.y + v1.y) + v2.y) + v3.y;
            float s2 = ((v0.z + v1.z) + v2.z) + v3.z;
            float s3 = ((v0.w + v1.w) + v2.w) + v3.w;
            int c = cq * 16 + i * 4;
            ob[(size_t)(c + 0) * HW + p] = s0;
            ob[(size_t)(c + 1) * HW + p] = s1;
            ob[(size_t)(c + 2) * HW + p] = s2;
            ob[(size_t)(c + 3) * HW + p] = s3;
        }

        // indices (wave 0; e0..e3 already in registers)
        if (tid < BPTS)
            ((float4*)out_idx)[n0 + p] =
                make_float4((float)e0, (float)e1, (float)e2, (float)e3);
    }
}

extern "C" void kernel_launch(void* const* d_in, const int* in_sizes, int n_in,
                              void* d_out, int out_size, void* d_ws, size_t ws_size,
                              hipStream_t stream) {
    const float* x  = (const float*)d_in[0];
    const float* cb = (const float*)d_in[1];
    float* out       = (float*)d_out;
    float* out_quant = out;                    // 8388608
    float* out_idx   = out + 8388608;          // 524288
    float* out_loss  = out + 8388608 + 524288; // 4

    float* cbS = (float*)d_ws;                 // 64*512 floats
    float* csq = cbS + CH * KCODE;             // 512 floats (striped -csq/2)

    hipMemsetAsync(out_loss, 0, NQ * sizeof(float), stream);
    prep_cbS<<<(CH * KCODE) / 256, 256, 0, stream>>>(cb, cbS);
    prep_csq<<<2, 256, 0, stream>>>(cb, csq);
    rvq_main<<<NPTS / BPTS, BTHR, 0, stream>>>(x, cb, cbS, csq,
                                               out_quant, out_idx, out_loss);
}